// Round 6
// baseline (145.227 us; speedup 1.0000x reference)
//
#include <hip/hip_runtime.h>
#include <hip/hip_bf16.h>
#include <math.h>

// ================= complex float helpers (prep, in-kernel) =================
struct cf { float x, y; };
__device__ __forceinline__ cf cfmul(cf a, cf b){ return {a.x*b.x - a.y*b.y, a.x*b.y + a.y*b.x}; }
__device__ __forceinline__ cf cfconj(cf a){ return {a.x, -a.y}; }
__device__ __forceinline__ cf cfadd(cf a, cf b){ return {a.x+b.x, a.y+b.y}; }

// S[d'*4+d] = sum_K K[i',a] * conj(K[j',b]),  d'=2i'+j', d=2a+b  (ket = high bit)
__device__ void superop_f(cf S[16], const cf* Ks, int nk){
    for (int i=0;i<16;i++) S[i] = {0.f,0.f};
    for (int n=0;n<nk;n++){
        const cf* K = Ks + n*4;
        for (int ip=0; ip<2; ip++) for (int jp=0; jp<2; jp++)
        for (int a=0; a<2; a++)   for (int b=0; b<2; b++){
            cf t = cfmul(K[ip*2+a], cfconj(K[jp*2+b]));
            int idx = (ip*2+jp)*4 + (a*2+b);
            S[idx] = cfadd(S[idx], t);
        }
    }
}

__device__ void mm4f(cf C[16], const cf A[16], const cf B[16]){
    for (int i=0;i<4;i++) for (int j=0;j<4;j++){
        cf s = {0.f,0.f};
        for (int k=0;k<4;k++) s = cfadd(s, cfmul(A[i*4+k], B[k*4+j]));
        C[i*4+j] = s;
    }
}

__device__ void build_dep_f(cf* dep, float p){
    float a = sqrtf(1.f-p), b = sqrtf(p/3.f);
    dep[0]={a,0.f};  dep[1]={0.f,0.f};  dep[2]={0.f,0.f}; dep[3]={a,0.f};    // I
    dep[4]={0.f,0.f};dep[5]={b,0.f};    dep[6]={b,0.f};   dep[7]={0.f,0.f};  // X
    dep[8]={0.f,0.f};dep[9]={0.f,-b};   dep[10]={0.f,b};  dep[11]={0.f,0.f}; // Y
    dep[12]={b,0.f}; dep[13]={0.f,0.f}; dep[14]={0.f,0.f};dep[15]={-b,0.f};  // Z
}

// in-kernel prep: threads 0..30 fill sm[0..495]
// sm[(l*10+q)*16 .. +15] = N1 * Rot(l,q); sm[480..495] = N2
__device__ void prep_sm(float2* sm, const float* __restrict__ wts, int tid){
    if (tid < 31){
        const float GA = -expm1f(-2.0000000000000002e-06f);   // 1-exp(-GATE/T1)
        const float GP = -expm1f(-1.4285714285714286e-06f);   // 1-exp(-GATE/T2)
        cf amp[8], ph[8], kr[16];
        { float s1=sqrtf(1.f-GA), s2=sqrtf(GA);
          amp[0]={1.f,0.f}; amp[1]={0.f,0.f}; amp[2]={0.f,0.f}; amp[3]={s1,0.f};
          amp[4]={0.f,0.f}; amp[5]={s2,0.f};  amp[6]={0.f,0.f}; amp[7]={0.f,0.f}; }
        { float s1=sqrtf(1.f-GP), s2=sqrtf(GP);
          ph[0]={1.f,0.f}; ph[1]={0.f,0.f}; ph[2]={0.f,0.f}; ph[3]={s1,0.f};
          ph[4]={0.f,0.f}; ph[5]={0.f,0.f}; ph[6]={0.f,0.f}; ph[7]={s2,0.f}; }
        cf Sdep[16], Samp[16], Sph[16], NN[16], tmp[16];
        superop_f(Samp, amp, 2);
        superop_f(Sph, ph, 2);
        if (tid == 30){
            build_dep_f(kr, 0.01f); superop_f(Sdep, kr, 4);
            mm4f(tmp, Samp, Sdep); mm4f(NN, Sph, tmp);        // N2
            for (int i=0;i<16;i++) sm[480+i] = make_float2(NN[i].x, NN[i].y);
        } else {
            build_dep_f(kr, 0.001f); superop_f(Sdep, kr, 4);
            mm4f(tmp, Samp, Sdep); mm4f(NN, Sph, tmp);        // N1
            float phi = wts[tid*3+0], th = wts[tid*3+1], om = wts[tid*3+2];
            float ct = cosf(0.5f*th), st = sinf(0.5f*th);
            cf ep = {cosf(0.5f*(phi+om)), -sinf(0.5f*(phi+om))};
            cf em = {cosf(0.5f*(phi-om)),  sinf(0.5f*(phi-om))};
            cf R[4];
            R[0] = { ep.x*ct,  ep.y*ct};
            R[1] = {-em.x*st, -em.y*st};
            R[2] = { em.x*st, -em.y*st};
            R[3] = { ep.x*ct, -ep.y*ct};
            cf Sr[16];
            for (int i2=0;i2<2;i2++) for (int j2=0;j2<2;j2++)
            for (int a=0;a<2;a++)    for (int b2=0;b2<2;b2++)
                Sr[(i2*2+j2)*4+(a*2+b2)] = cfmul(R[i2*2+a], cfconj(R[j2*2+b2]));
            cf S[16]; mm4f(S, NN, Sr);
            for (int i=0;i<16;i++) sm[tid*16+i] = make_float2(S[i].x, S[i].y);
        }
    }
}

__device__ __forceinline__ unsigned spread2(unsigned x){
    x = (x | (x<<8)) & 0x00FF00FFu;
    x = (x | (x<<4)) & 0x0F0F0F0Fu;
    x = (x | (x<<2)) & 0x33333333u;
    x = (x | (x<<1)) & 0x55555555u;
    return x;
}

#define CMUL_ACC(re,im,m,a) { re += (m).x*(a).x - (m).y*(a).y; im += (m).x*(a).y + (m).y*(a).x; }

#define ALONG_A(Mp) { _Pragma("unroll") for (int db_=0; db_<4; db_++){ \
    float2 a0=v[db_], a1=v[4+db_], a2=v[8+db_], a3=v[12+db_]; \
    _Pragma("unroll") for (int dp_=0; dp_<4; dp_++){ \
        float re=0.f, im=0.f; \
        CMUL_ACC(re,im,(Mp)[dp_*4+0],a0); CMUL_ACC(re,im,(Mp)[dp_*4+1],a1); \
        CMUL_ACC(re,im,(Mp)[dp_*4+2],a2); CMUL_ACC(re,im,(Mp)[dp_*4+3],a3); \
        v[dp_*4+db_] = make_float2(re,im); } } }

#define ALONG_B(Mp) { _Pragma("unroll") for (int da_=0; da_<4; da_++){ \
    float2 a0=v[da_*4+0], a1=v[da_*4+1], a2=v[da_*4+2], a3=v[da_*4+3]; \
    _Pragma("unroll") for (int dp_=0; dp_<4; dp_++){ \
        float re=0.f, im=0.f; \
        CMUL_ACC(re,im,(Mp)[dp_*4+0],a0); CMUL_ACC(re,im,(Mp)[dp_*4+1],a1); \
        CMUL_ACC(re,im,(Mp)[dp_*4+2],a2); CMUL_ACC(re,im,(Mp)[dp_*4+3],a3); \
        v[da_*4+dp_] = make_float2(re,im); } } }

#define WRED64(s) { s += __shfl_down(s,32); s += __shfl_down(s,16); s += __shfl_down(s,8); \
                    s += __shfl_down(s,4);  s += __shfl_down(s,2);  s += __shfl_down(s,1); }

// ================= fused phase kernel =================
// rho layout (float2 index, 20 bits): digit d at position p(d):
//   p: d9->0, d4->1, d5->2, d6->3, d7->4, d8->5, d0->6, d1->7, d2->8, d3->9.
//   digit at position p occupies bits (2p = bra, 2p+1 = ket).
// Phase A (isB=0): tile = bits 0..11 (digits d9,d4,d5..d8); block -> bits 12..19.
// Phase B (isB=1): tile = bits 0..3 + 12..19 (digits d9,d4,d0..d3); block -> bits 4..11.
// mode: 0 = normal; 1 = also zero cvec (block 0); 2 = fused partial trace, skip rho store.
__global__ void __launch_bounds__(256)
fused6(float2* __restrict__ rho, const float* __restrict__ wts, float* __restrict__ cvec,
       int layer, int isB, int doInit, int mode)
{
    __shared__ __align__(16) float2 tile[4096];
    __shared__ float2 sm[31*16];
    int tid = threadIdx.x;
    unsigned blk = blockIdx.x;

    if (mode == 1 && blk == 0 && tid < 20) cvec[tid] = 0.f;

    unsigned bo = blk << (isB ? 4 : 12);

    // stage global loads into regs FIRST so prep_sm's serial wave-0 work hides under them
    float4 ld[8];
    if (!doInit){
#pragma unroll
        for (int r=0; r<8; r++){
            unsigned u = 2u*(tid + 256u*r);
            unsigned g = isB ? ((u & 14u) | ((u >> 4) << 12) | bo) : (u | bo);
            ld[r] = *reinterpret_cast<const float4*>(rho + g);
        }
    }

    prep_sm(sm, wts, tid);

    if (doInit){
#pragma unroll
        for (int r=0; r<16; r++){
            unsigned u = tid + 256u*r;
            float val = (blk==0 && u==0) ? 1.f : 0.f;
            tile[u ^ ((u>>6)&62u)] = make_float2(val, 0.f);
        }
    } else {
#pragma unroll
        for (int r=0; r<8; r++){
            unsigned u = 2u*(tid + 256u*r);
            unsigned s = u ^ ((u>>6)&62u);
            *reinterpret_cast<float4*>(&tile[s]) = ld[r];
        }
    }
    __syncthreads();

    // op tables (tile bit positions of control/target digit pairs)
    const int A_PA[5] = {0,10,8,6,4}, A_PB[5] = {10,8,6,4,2};
    const int B_PA[5] = {2,10,8,6,4}, B_PB[5] = {10,8,6,4,0};

#pragma unroll
    for (int i=0; i<5; i++){
        int pa = isB ? B_PA[i] : A_PA[i];
        int pb = isB ? B_PB[i] : A_PB[i];
        int mA = (!isB && i==0) ? layer*160 : -1;                 // rot(l,0) on d9 control
        int mB;
        if (!isB) mB = (layer*10 + i + 1)*16;                      // rot(l,1..5)
        else      mB = (i < 4) ? (layer*10 + 6 + i)*16 : -1;       // rot(l,6..9), none on last
        int lo = pa < pb ? pa : pb, hi = pa < pb ? pb : pa;
        unsigned g8 = (unsigned)tid;
        unsigned xx = ((g8 >> lo) << (lo+2)) | (g8 & ((1u<<lo)-1u));
        xx = ((xx >> hi) << (hi+2)) | (xx & ((1u<<hi)-1u));
        unsigned adr[16];
        float2 v[16];
#pragma unroll
        for (int d=0; d<16; d++){
            unsigned t = xx | ((unsigned)(d>>2) << pa) | ((unsigned)(d&3) << pb);
            adr[d] = t ^ ((t>>6)&62u);
            v[d] = tile[adr[d]];
        }
        if (mA >= 0) { const float2* M = sm + mA; ALONG_A(M); }
        if (mB >= 0) { const float2* M = sm + mB; ALONG_B(M); }
        { // CNOT perm: v[da][db] <- v[da][db^da]
            float2 t0;
            t0=v[4];  v[4]=v[5];   v[5]=t0;
            t0=v[6];  v[6]=v[7];   v[7]=t0;
            t0=v[8];  v[8]=v[10];  v[10]=t0;
            t0=v[9];  v[9]=v[11];  v[11]=t0;
            t0=v[12]; v[12]=v[15]; v[15]=t0;
            t0=v[13]; v[13]=v[14]; v[14]=t0;
        }
        { const float2* M = sm + 480; ALONG_B(M); ALONG_A(M); }   // N2 target, N2 control
#pragma unroll
        for (int d=0; d<16; d++) tile[adr[d]] = v[d];
        __syncthreads();
    }

    if (mode != 2){
#pragma unroll
        for (int r=0; r<8; r++){
            unsigned u = 2u*(tid + 256u*r);
            unsigned g = isB ? ((u & 14u) | ((u >> 4) << 12) | bo) : (u | bo);
            unsigned s = u ^ ((u>>6)&62u);
            *reinterpret_cast<float4*>(rho + g) = *reinterpret_cast<const float4*>(&tile[s]);
        }
        return;
    }

    // ---- mode 2 (phase B, last layer): fused partial trace from the LDS tile ----
    // Tile slot i (bit pair 2i,2i+1) -> qubit: {0,5,9,8,7,6}. Block pair j -> qubit {4,3,2,1}.
    // rho is dead after this: no store.
    if (tid < 64){
        const int TQ[6] = {0,5,9,8,7,6};
        const int BQ[4] = {4,3,2,1};
        // block eligibility (wave-uniform)
        int noff = 0, joff = 0;
        bool bneg[4];
#pragma unroll
        for (int j=0; j<4; j++){
            unsigned bd = (blk >> (2*j)) & 3u;
            bneg[j] = (bd == 3u);
            if (bd == 1u || bd == 2u){ noff++; joff = j; }
        }
        if (noff <= 1){
            unsigned c = (unsigned)tid;                 // 6-bit diag config
            unsigned dcfg = 3u * spread2(c);
            float vd = tile[dcfg ^ ((dcfg>>6)&62u)].x;

            // X entries: slot i off-diagonal (v in {1,2}), others diagonal
            float xv[6];
#pragma unroll
            for (int i=0; i<6; i++){
                unsigned c5 = c & 31u;
                unsigned vv = 1u + (c >> 5);            // 1 or 2
                unsigned c6 = ((c5 >> i) << (i+1)) | (c5 & ((1u<<i)-1u));
                unsigned idx = 3u * spread2(c6) + (vv << (2*i));
                xv[i] = tile[idx ^ ((idx>>6)&62u)].x;
            }

            // Walsh-Hadamard butterfly over the 6 config bits:
            // lane 0 -> sum (T0); lane 2^i -> Z-signed sum for slot i
            float h = vd;
#pragma unroll
            for (int s=1; s<64; s<<=1){
                float o = __shfl_xor(h, s);
                h = (tid & s) ? (o - h) : (h + o);
            }

            if (noff == 0){
                // Z of tile qubits: lane 2^i holds the signed sum
#pragma unroll
                for (int i=0; i<6; i++)
                    if (tid == (1<<i)) atomicAdd(&cvec[2*TQ[i]+1], h);
                // X of tile qubits
#pragma unroll
                for (int i=0; i<6; i++){
                    float rx = xv[i];
                    WRED64(rx);
                    if (tid == 0) atomicAdd(&cvec[2*TQ[i]], rx);
                }
                // Z of block qubits: +-T0 (lane 0 holds T0)
                if (tid == 0){
#pragma unroll
                    for (int j=0; j<4; j++)
                        atomicAdd(&cvec[2*BQ[j]+1], bneg[j] ? -h : h);
                }
            } else {
                // exactly one off-diagonal block digit: X of that block qubit, += T0
                if (tid == 0) atomicAdd(&cvec[2*BQ[joff]], h);
            }
        }
    }
}

// ================= head: logits + sigmoid =================
__global__ void __launch_bounds__(256)
logits_kernel(const float* __restrict__ x, const float* __restrict__ bvec,
              const float* __restrict__ cvec, const float* __restrict__ w,
              float* __restrict__ out)
{
    __shared__ float xs[1024];
    __shared__ float cX[10], cZ[10];
    __shared__ float red[4];
    int b = blockIdx.x, tid = threadIdx.x;
    if (tid < 10){
        cX[tid] = w[2*tid] * cvec[2*tid];
        cZ[tid] = 0.96f * w[2*tid+1] * cvec[2*tid+1];   // readout bitflip folded: Z *= 1-2*0.02
    }
    {
        float4 xv = reinterpret_cast<const float4*>(x + (size_t)b*1024)[tid];
        float4 bv = reinterpret_cast<const float4*>(bvec)[tid];
        xs[tid*4+0] = xv.x + bv.x;
        xs[tid*4+1] = xv.y + bv.y;
        xs[tid*4+2] = xv.z + bv.z;
        xs[tid*4+3] = xv.w + bv.w;
    }
    __syncthreads();
    float acc = 0.f;
#pragma unroll
    for (int r=0; r<4; r++){
        int m = tid + r*256;
        float xm = xs[m];
        float sd = 0.f;
#pragma unroll
        for (int qq=0; qq<10; qq++){
            float cz = cZ[qq];
            sd += (m & (1<<(9-qq))) ? -cz : cz;
            acc += cX[qq] * xm * xs[m ^ (1<<(9-qq))];
        }
        acc += sd * xm * xm;
    }
    for (int o=32; o>0; o>>=1) acc += __shfl_down(acc, o);
    if ((tid & 63) == 0) red[tid>>6] = acc;
    __syncthreads();
    if (tid == 0){
        float l = red[0]+red[1]+red[2]+red[3];
        out[b] = 1.f / (1.f + expf(-l));
    }
}

// ================= launch =================
extern "C" void kernel_launch(void* const* d_in, const int* in_sizes, int n_in,
                              void* d_out, int out_size, void* d_ws, size_t ws_size,
                              hipStream_t stream) {
    const float* x    = (const float*)d_in[0];   // [2048,1024]
    const float* bvec = (const float*)d_in[1];   // [1024]
    const float* w    = (const float*)d_in[2];   // [20]
    const float* cw   = (const float*)d_in[3];   // [3,10,3]
    float* out = (float*)d_out;

    char* ws = (char*)d_ws;
    float2* rho  = (float2*)ws;                                   // 2^20 float2 = 8 MB
    float*  cvec = (float*)(ws + (size_t)(1u<<20)*sizeof(float2));
    (void)ws_size; (void)in_sizes; (void)n_in; (void)out_size;

    for (int l=0; l<3; l++){
        fused6<<<256, 256, 0, stream>>>(rho, cw, cvec, l, 0, (l==0) ? 1 : 0, (l==2) ? 1 : 0);
        fused6<<<256, 256, 0, stream>>>(rho, cw, cvec, l, 1, 0, (l==2) ? 2 : 0);
    }
    logits_kernel<<<2048, 256, 0, stream>>>(x, bvec, cvec, w, out);
}

// Round 7
// 121.892 us; speedup vs baseline: 1.1914x; 1.1914x over previous
//
#include <hip/hip_runtime.h>
#include <hip/hip_bf16.h>
#include <math.h>

// ================= complex float helpers (prep, in-kernel) =================
struct cf { float x, y; };
__device__ __forceinline__ cf cfmul(cf a, cf b){ return {a.x*b.x - a.y*b.y, a.x*b.y + a.y*b.x}; }
__device__ __forceinline__ cf cfconj(cf a){ return {a.x, -a.y}; }
__device__ __forceinline__ cf cfadd(cf a, cf b){ return {a.x+b.x, a.y+b.y}; }

// S[d'*4+d] = sum_K K[i',a] * conj(K[j',b]),  d'=2i'+j', d=2a+b  (ket = high bit)
__device__ void superop_f(cf S[16], const cf* Ks, int nk){
    for (int i=0;i<16;i++) S[i] = {0.f,0.f};
    for (int n=0;n<nk;n++){
        const cf* K = Ks + n*4;
        for (int ip=0; ip<2; ip++) for (int jp=0; jp<2; jp++)
        for (int a=0; a<2; a++)   for (int b=0; b<2; b++){
            cf t = cfmul(K[ip*2+a], cfconj(K[jp*2+b]));
            int idx = (ip*2+jp)*4 + (a*2+b);
            S[idx] = cfadd(S[idx], t);
        }
    }
}

__device__ void mm4f(cf C[16], const cf A[16], const cf B[16]){
    for (int i=0;i<4;i++) for (int j=0;j<4;j++){
        cf s = {0.f,0.f};
        for (int k=0;k<4;k++) s = cfadd(s, cfmul(A[i*4+k], B[k*4+j]));
        C[i*4+j] = s;
    }
}

__device__ void build_dep_f(cf* dep, float p){
    float a = sqrtf(1.f-p), b = sqrtf(p/3.f);
    dep[0]={a,0.f};  dep[1]={0.f,0.f};  dep[2]={0.f,0.f}; dep[3]={a,0.f};    // I
    dep[4]={0.f,0.f};dep[5]={b,0.f};    dep[6]={b,0.f};   dep[7]={0.f,0.f};  // X
    dep[8]={0.f,0.f};dep[9]={0.f,-b};   dep[10]={0.f,b};  dep[11]={0.f,0.f}; // Y
    dep[12]={b,0.f}; dep[13]={0.f,0.f}; dep[14]={0.f,0.f};dep[15]={-b,0.f};  // Z
}

// in-kernel prep: threads 0..30 fill sm[0..495]
// sm[(l*10+q)*16 .. +15] = N1 * Rot(l,q); sm[480..495] = N2
__device__ void prep_sm(float2* sm, const float* __restrict__ wts, int tid){
    if (tid < 31){
        const float GA = -expm1f(-2.0000000000000002e-06f);   // 1-exp(-GATE/T1)
        const float GP = -expm1f(-1.4285714285714286e-06f);   // 1-exp(-GATE/T2)
        cf amp[8], ph[8], kr[16];
        { float s1=sqrtf(1.f-GA), s2=sqrtf(GA);
          amp[0]={1.f,0.f}; amp[1]={0.f,0.f}; amp[2]={0.f,0.f}; amp[3]={s1,0.f};
          amp[4]={0.f,0.f}; amp[5]={s2,0.f};  amp[6]={0.f,0.f}; amp[7]={0.f,0.f}; }
        { float s1=sqrtf(1.f-GP), s2=sqrtf(GP);
          ph[0]={1.f,0.f}; ph[1]={0.f,0.f}; ph[2]={0.f,0.f}; ph[3]={s1,0.f};
          ph[4]={0.f,0.f}; ph[5]={0.f,0.f}; ph[6]={0.f,0.f}; ph[7]={s2,0.f}; }
        cf Sdep[16], Samp[16], Sph[16], NN[16], tmp[16];
        superop_f(Samp, amp, 2);
        superop_f(Sph, ph, 2);
        if (tid == 30){
            build_dep_f(kr, 0.01f); superop_f(Sdep, kr, 4);
            mm4f(tmp, Samp, Sdep); mm4f(NN, Sph, tmp);        // N2
            for (int i=0;i<16;i++) sm[480+i] = make_float2(NN[i].x, NN[i].y);
        } else {
            build_dep_f(kr, 0.001f); superop_f(Sdep, kr, 4);
            mm4f(tmp, Samp, Sdep); mm4f(NN, Sph, tmp);        // N1
            float phi = wts[tid*3+0], th = wts[tid*3+1], om = wts[tid*3+2];
            float ct = cosf(0.5f*th), st = sinf(0.5f*th);
            cf ep = {cosf(0.5f*(phi+om)), -sinf(0.5f*(phi+om))};
            cf em = {cosf(0.5f*(phi-om)),  sinf(0.5f*(phi-om))};
            cf R[4];
            R[0] = { ep.x*ct,  ep.y*ct};
            R[1] = {-em.x*st, -em.y*st};
            R[2] = { em.x*st, -em.y*st};
            R[3] = { ep.x*ct, -ep.y*ct};
            cf Sr[16];
            for (int i2=0;i2<2;i2++) for (int j2=0;j2<2;j2++)
            for (int a=0;a<2;a++)    for (int b2=0;b2<2;b2++)
                Sr[(i2*2+j2)*4+(a*2+b2)] = cfmul(R[i2*2+a], cfconj(R[j2*2+b2]));
            cf S[16]; mm4f(S, NN, Sr);
            for (int i=0;i<16;i++) sm[tid*16+i] = make_float2(S[i].x, S[i].y);
        }
    }
}

__device__ __forceinline__ unsigned spread2(unsigned x){
    x = (x | (x<<8)) & 0x00FF00FFu;
    x = (x | (x<<4)) & 0x0F0F0F0Fu;
    x = (x | (x<<2)) & 0x33333333u;
    x = (x | (x<<1)) & 0x55555555u;
    return x;
}

#define CMUL_ACC(re,im,m,a) { re += (m).x*(a).x - (m).y*(a).y; im += (m).x*(a).y + (m).y*(a).x; }

#define ALONG_A(Mp) { _Pragma("unroll") for (int db_=0; db_<4; db_++){ \
    float2 a0=v[db_], a1=v[4+db_], a2=v[8+db_], a3=v[12+db_]; \
    _Pragma("unroll") for (int dp_=0; dp_<4; dp_++){ \
        float re=0.f, im=0.f; \
        CMUL_ACC(re,im,(Mp)[dp_*4+0],a0); CMUL_ACC(re,im,(Mp)[dp_*4+1],a1); \
        CMUL_ACC(re,im,(Mp)[dp_*4+2],a2); CMUL_ACC(re,im,(Mp)[dp_*4+3],a3); \
        v[dp_*4+db_] = make_float2(re,im); } } }

#define ALONG_B(Mp) { _Pragma("unroll") for (int da_=0; da_<4; da_++){ \
    float2 a0=v[da_*4+0], a1=v[da_*4+1], a2=v[da_*4+2], a3=v[da_*4+3]; \
    _Pragma("unroll") for (int dp_=0; dp_<4; dp_++){ \
        float re=0.f, im=0.f; \
        CMUL_ACC(re,im,(Mp)[dp_*4+0],a0); CMUL_ACC(re,im,(Mp)[dp_*4+1],a1); \
        CMUL_ACC(re,im,(Mp)[dp_*4+2],a2); CMUL_ACC(re,im,(Mp)[dp_*4+3],a3); \
        v[da_*4+dp_] = make_float2(re,im); } } }

#define WRED64(s) { s += __shfl_down(s,32); s += __shfl_down(s,16); s += __shfl_down(s,8); \
                    s += __shfl_down(s,4);  s += __shfl_down(s,2);  s += __shfl_down(s,1); }

// ================= fused phase kernel (fully specialized) =================
// rho layout (float2 index, 20 bits): digit d at position p(d):
//   p: d9->0, d4->1, d5->2, d6->3, d7->4, d8->5, d0->6, d1->7, d2->8, d3->9.
//   digit at position p occupies bits (2p = bra, 2p+1 = ket).
// Phase A (ISB=0): tile = bits 0..11 (digits d9,d4,d5..d8); block -> bits 12..19.
// Phase B (ISB=1): tile = bits 0..3 + 12..19 (digits d9,d4,d0..d3); block -> bits 4..11.
// MODE: 0 = normal; 1 = also zero cvec (block 0); 2 = fused partial trace, skip rho store.
template<int LAYER, int ISB, int DOINIT, int MODE>
__global__ void __launch_bounds__(256)
fused6(float2* __restrict__ rho, const float* __restrict__ wts, float* __restrict__ cvec)
{
    __shared__ __align__(16) float2 tile[4096];
    __shared__ float2 sm[31*16];
    int tid = threadIdx.x;
    unsigned blk = blockIdx.x;

    if (MODE == 1 && blk == 0 && tid < 20) cvec[tid] = 0.f;

    prep_sm(sm, wts, tid);      // wave 0 only; waves 1-3 fall through to loads

    unsigned bo = blk << (ISB ? 4 : 12);
    if (DOINIT){
#pragma unroll
        for (int r=0; r<16; r++){
            unsigned u = tid + 256u*r;
            float val = (blk==0 && u==0) ? 1.f : 0.f;
            tile[u ^ ((u>>6)&62u)] = make_float2(val, 0.f);
        }
    } else {
#pragma unroll
        for (int r=0; r<8; r++){
            unsigned u = 2u*(tid + 256u*r);
            unsigned g = ISB ? ((u & 14u) | ((u >> 4) << 12) | bo) : (u | bo);
            unsigned s = u ^ ((u>>6)&62u);
            *reinterpret_cast<float4*>(&tile[s]) = *reinterpret_cast<const float4*>(rho + g);
        }
    }
    __syncthreads();

    // op tables (tile bit positions of control/target digit pairs) — compile-time
    constexpr int A_PA[5] = {0,10,8,6,4}, A_PB[5] = {10,8,6,4,2};
    constexpr int B_PA[5] = {2,10,8,6,4}, B_PB[5] = {10,8,6,4,0};

#pragma unroll
    for (int i=0; i<5; i++){
        const int pa = ISB ? B_PA[i] : A_PA[i];
        const int pb = ISB ? B_PB[i] : A_PB[i];
        const int mA = (!ISB && i==0) ? LAYER*160 : -1;               // rot(l,0) on d9 control
        const int mB = !ISB ? (LAYER*10 + i + 1)*16
                            : ((i < 4) ? (LAYER*10 + 6 + i)*16 : -1); // rot(l,6..9), none on last
        const int lo = pa < pb ? pa : pb, hi = pa < pb ? pb : pa;
        unsigned g8 = (unsigned)tid;
        unsigned xx = ((g8 >> lo) << (lo+2)) | (g8 & ((1u<<lo)-1u));
        xx = ((xx >> hi) << (hi+2)) | (xx & ((1u<<hi)-1u));
        unsigned adr[16];
        float2 v[16];
#pragma unroll
        for (int d=0; d<16; d++){
            unsigned t = xx | ((unsigned)(d>>2) << pa) | ((unsigned)(d&3) << pb);
            adr[d] = t ^ ((t>>6)&62u);
            v[d] = tile[adr[d]];
        }
        if (mA >= 0) { const float2* M = sm + mA; ALONG_A(M); }
        if (mB >= 0) { const float2* M = sm + mB; ALONG_B(M); }
        { // CNOT perm: v[da][db] <- v[da][db^da]
            float2 t0;
            t0=v[4];  v[4]=v[5];   v[5]=t0;
            t0=v[6];  v[6]=v[7];   v[7]=t0;
            t0=v[8];  v[8]=v[10];  v[10]=t0;
            t0=v[9];  v[9]=v[11];  v[11]=t0;
            t0=v[12]; v[12]=v[15]; v[15]=t0;
            t0=v[13]; v[13]=v[14]; v[14]=t0;
        }
        { const float2* M = sm + 480; ALONG_B(M); ALONG_A(M); }   // N2 target, N2 control
#pragma unroll
        for (int d=0; d<16; d++) tile[adr[d]] = v[d];
        __syncthreads();
    }

    if (MODE != 2){
#pragma unroll
        for (int r=0; r<8; r++){
            unsigned u = 2u*(tid + 256u*r);
            unsigned g = ISB ? ((u & 14u) | ((u >> 4) << 12) | bo) : (u | bo);
            unsigned s = u ^ ((u>>6)&62u);
            *reinterpret_cast<float4*>(rho + g) = *reinterpret_cast<const float4*>(&tile[s]);
        }
        return;
    }

    // ---- MODE 2 (phase B, last layer): fused partial trace from the LDS tile ----
    // Tile slot i (bit pair 2i,2i+1) -> qubit: {0,5,9,8,7,6}. Block pair j -> qubit {4,3,2,1}.
    // rho is dead after this: no store.
    if (tid < 64){
        const int TQ[6] = {0,5,9,8,7,6};
        const int BQ[4] = {4,3,2,1};
        // block eligibility (wave-uniform)
        int noff = 0, joff = 0;
        bool bneg[4];
#pragma unroll
        for (int j=0; j<4; j++){
            unsigned bd = (blk >> (2*j)) & 3u;
            bneg[j] = (bd == 3u);
            if (bd == 1u || bd == 2u){ noff++; joff = j; }
        }
        if (noff <= 1){
            unsigned c = (unsigned)tid;                 // 6-bit diag config
            unsigned dcfg = 3u * spread2(c);
            float vd = tile[dcfg ^ ((dcfg>>6)&62u)].x;

            // X entries: slot i off-diagonal (v in {1,2}), others diagonal
            float xv[6];
#pragma unroll
            for (int i=0; i<6; i++){
                unsigned c5 = c & 31u;
                unsigned vv = 1u + (c >> 5);            // 1 or 2
                unsigned c6 = ((c5 >> i) << (i+1)) | (c5 & ((1u<<i)-1u));
                unsigned idx = 3u * spread2(c6) + (vv << (2*i));
                xv[i] = tile[idx ^ ((idx>>6)&62u)].x;
            }

            // Walsh-Hadamard butterfly over the 6 config bits:
            // lane 0 -> sum (T0); lane 2^i -> Z-signed sum for slot i
            float h = vd;
#pragma unroll
            for (int s=1; s<64; s<<=1){
                float o = __shfl_xor(h, s);
                h = (tid & s) ? (o - h) : (h + o);
            }

            if (noff == 0){
                // Z of tile qubits: lane 2^i holds the signed sum
#pragma unroll
                for (int i=0; i<6; i++)
                    if (tid == (1<<i)) atomicAdd(&cvec[2*TQ[i]+1], h);
                // X of tile qubits
#pragma unroll
                for (int i=0; i<6; i++){
                    float rx = xv[i];
                    WRED64(rx);
                    if (tid == 0) atomicAdd(&cvec[2*TQ[i]], rx);
                }
                // Z of block qubits: +-T0 (lane 0 holds T0)
                if (tid == 0){
#pragma unroll
                    for (int j=0; j<4; j++)
                        atomicAdd(&cvec[2*BQ[j]+1], bneg[j] ? -h : h);
                }
            } else {
                // exactly one off-diagonal block digit: X of that block qubit, += T0
                if (tid == 0) atomicAdd(&cvec[2*BQ[joff]], h);
            }
        }
    }
}

// ================= head: logits + sigmoid =================
__global__ void __launch_bounds__(256)
logits_kernel(const float* __restrict__ x, const float* __restrict__ bvec,
              const float* __restrict__ cvec, const float* __restrict__ w,
              float* __restrict__ out)
{
    __shared__ float xs[1024];
    __shared__ float cX[10], cZ[10];
    __shared__ float red[4];
    int b = blockIdx.x, tid = threadIdx.x;
    if (tid < 10){
        cX[tid] = w[2*tid] * cvec[2*tid];
        cZ[tid] = 0.96f * w[2*tid+1] * cvec[2*tid+1];   // readout bitflip folded: Z *= 1-2*0.02
    }
    {
        float4 xv = reinterpret_cast<const float4*>(x + (size_t)b*1024)[tid];
        float4 bv = reinterpret_cast<const float4*>(bvec)[tid];
        xs[tid*4+0] = xv.x + bv.x;
        xs[tid*4+1] = xv.y + bv.y;
        xs[tid*4+2] = xv.z + bv.z;
        xs[tid*4+3] = xv.w + bv.w;
    }
    __syncthreads();
    float acc = 0.f;
#pragma unroll
    for (int r=0; r<4; r++){
        int m = tid + r*256;
        float xm = xs[m];
        float sd = 0.f;
#pragma unroll
        for (int qq=0; qq<10; qq++){
            float cz = cZ[qq];
            sd += (m & (1<<(9-qq))) ? -cz : cz;
            acc += cX[qq] * xm * xs[m ^ (1<<(9-qq))];
        }
        acc += sd * xm * xm;
    }
    for (int o=32; o>0; o>>=1) acc += __shfl_down(acc, o);
    if ((tid & 63) == 0) red[tid>>6] = acc;
    __syncthreads();
    if (tid == 0){
        float l = red[0]+red[1]+red[2]+red[3];
        out[b] = 1.f / (1.f + expf(-l));
    }
}

// ================= launch =================
extern "C" void kernel_launch(void* const* d_in, const int* in_sizes, int n_in,
                              void* d_out, int out_size, void* d_ws, size_t ws_size,
                              hipStream_t stream) {
    const float* x    = (const float*)d_in[0];   // [2048,1024]
    const float* bvec = (const float*)d_in[1];   // [1024]
    const float* w    = (const float*)d_in[2];   // [20]
    const float* cw   = (const float*)d_in[3];   // [3,10,3]
    float* out = (float*)d_out;

    char* ws = (char*)d_ws;
    float2* rho  = (float2*)ws;                                   // 2^20 float2 = 8 MB
    float*  cvec = (float*)(ws + (size_t)(1u<<20)*sizeof(float2));
    (void)ws_size; (void)in_sizes; (void)n_in; (void)out_size;

    fused6<0,0,1,0><<<256, 256, 0, stream>>>(rho, cw, cvec);
    fused6<0,1,0,0><<<256, 256, 0, stream>>>(rho, cw, cvec);
    fused6<1,0,0,0><<<256, 256, 0, stream>>>(rho, cw, cvec);
    fused6<1,1,0,0><<<256, 256, 0, stream>>>(rho, cw, cvec);
    fused6<2,0,0,1><<<256, 256, 0, stream>>>(rho, cw, cvec);
    fused6<2,1,0,2><<<256, 256, 0, stream>>>(rho, cw, cvec);
    logits_kernel<<<2048, 256, 0, stream>>>(x, bvec, cvec, w, out);
}

// Round 9
// 66.429 us; speedup vs baseline: 2.1862x; 1.8349x over previous
//
#include <hip/hip_runtime.h>
#include <hip/hip_bf16.h>
#include <math.h>

// ================= complex 2x2 helpers (prep only) =================
struct cf { float x, y; };
__device__ __forceinline__ cf cfmul(cf a, cf b){ return {a.x*b.x - a.y*b.y, a.x*b.y + a.y*b.x}; }
__device__ __forceinline__ cf cfconj(cf a){ return {a.x, -a.y}; }
__device__ __forceinline__ cf cfadd(cf a, cf b){ return {a.x+b.x, a.y+b.y}; }

__device__ __forceinline__ void pmat(int k, cf* P){
    if (k==0){ P[0]={1.f,0.f}; P[1]={0.f,0.f}; P[2]={0.f,0.f}; P[3]={1.f,0.f}; }
    else if (k==1){ P[0]={0.f,0.f}; P[1]={1.f,0.f}; P[2]={1.f,0.f}; P[3]={0.f,0.f}; }
    else if (k==2){ P[0]={0.f,0.f}; P[1]={0.f,-1.f}; P[2]={0.f,1.f}; P[3]={0.f,0.f}; }
    else { P[0]={1.f,0.f}; P[1]={0.f,0.f}; P[2]={0.f,0.f}; P[3]={-1.f,0.f}; }
}
__device__ void mul2(cf* C, const cf* A, const cf* B){
    C[0]=cfadd(cfmul(A[0],B[0]),cfmul(A[1],B[2]));
    C[1]=cfadd(cfmul(A[0],B[1]),cfmul(A[1],B[3]));
    C[2]=cfadd(cfmul(A[2],B[0]),cfmul(A[3],B[2]));
    C[3]=cfadd(cfmul(A[2],B[1]),cfmul(A[3],B[3]));
}
// T[t*4+s] += 0.5 * Re tr(P_t K P_s K^dagger)
__device__ void ptm_acc(float* T, const cf* K){
    cf Kd[4] = {cfconj(K[0]), cfconj(K[2]), cfconj(K[1]), cfconj(K[3])};
    for (int s=0;s<4;s++){
        cf Ps[4]; pmat(s,Ps);
        cf t1[4], t2[4];
        mul2(t1, K, Ps);
        mul2(t2, t1, Kd);
        for (int t=0;t<4;t++){
            cf Pt[4]; pmat(t,Pt);
            float re = Pt[0].x*t2[0].x - Pt[0].y*t2[0].y
                     + Pt[1].x*t2[2].x - Pt[1].y*t2[2].y
                     + Pt[2].x*t2[1].x - Pt[2].y*t2[1].y
                     + Pt[3].x*t2[3].x - Pt[3].y*t2[3].y;
            T[t*4+s] += 0.5f*re;
        }
    }
}
__device__ void rmm4(float* C, const float* A, const float* B){
    for (int i=0;i<4;i++) for (int j=0;j<4;j++){
        float s=0.f;
        for (int k=0;k<4;k++) s += A[i*4+k]*B[k*4+j];
        C[i*4+j]=s;
    }
}

// in-kernel prep: threads 0..30 fill sm[0..495] with REAL Pauli-transfer mats.
// sm[(l*10+q)*16..] = Tnoise1 * Trot(l,q); sm[480..] = Tnoise2 (N2).
// Noise PTMs closed-form: dep(p)=diag(1,f,f,f) f=1-4p/3; amp: X,Y*=sa, Z'=(1-GA)Z+GA*I;
// phase: X,Y*=spp. Composite Tn = Tph*Tamp*Tdep.
__device__ void prep_sm(float* sm, const float* __restrict__ wts, int tid){
    if (tid < 31){
        const float GA = -expm1f(-2.0000000000000002e-06f);   // 1-exp(-GATE/T1)
        const float GP = -expm1f(-1.4285714285714286e-06f);   // 1-exp(-GATE/T2)
        float sa = sqrtf(1.f-GA), spp = sqrtf(1.f-GP);
        float p = (tid==30) ? 0.01f : 0.001f;
        float f = 1.f - (4.f/3.f)*p;
        float Tn[16] = {0};
        Tn[0]      = 1.f;
        Tn[1*4+1]  = spp*sa*f;
        Tn[2*4+2]  = spp*sa*f;
        Tn[3*4+3]  = (1.f-GA)*f;
        Tn[3*4+0]  = GA;
        if (tid == 30){
            for (int i=0;i<16;i++) sm[480+i] = Tn[i];
        } else {
            float phi = wts[tid*3+0], th = wts[tid*3+1], om = wts[tid*3+2];
            float ct = cosf(0.5f*th), st = sinf(0.5f*th);
            cf ep = {cosf(0.5f*(phi+om)), -sinf(0.5f*(phi+om))};
            cf em = {cosf(0.5f*(phi-om)),  sinf(0.5f*(phi-om))};
            cf U[4];
            U[0] = { ep.x*ct,  ep.y*ct};
            U[1] = {-em.x*st, -em.y*st};
            U[2] = { em.x*st, -em.y*st};
            U[3] = { ep.x*ct, -ep.y*ct};
            float Tr[16] = {0};
            ptm_acc(Tr, U);                 // unitary: single Kraus
            float S[16]; rmm4(S, Tn, Tr);   // rot first, then noise
            for (int i=0;i<16;i++) sm[tid*16+i] = S[i];
        }
    }
}

// LDS swizzle on 12-bit float index: XOR bits 9..11 into 2..4 (float4-preserving)
__device__ __forceinline__ unsigned swz(unsigned t){ return t ^ ((t>>7)&0x1Cu); }

#define ALONG_A(Mp) { _Pragma("unroll") for (int db_=0; db_<4; db_++){ \
    float a0=v[db_], a1=v[4+db_], a2=v[8+db_], a3=v[12+db_]; \
    _Pragma("unroll") for (int dp_=0; dp_<4; dp_++){ \
        v[dp_*4+db_] = (Mp)[dp_*4+0]*a0 + (Mp)[dp_*4+1]*a1 + (Mp)[dp_*4+2]*a2 + (Mp)[dp_*4+3]*a3; } } }

#define ALONG_B(Mp) { _Pragma("unroll") for (int da_=0; da_<4; da_++){ \
    float a0=v[da_*4+0], a1=v[da_*4+1], a2=v[da_*4+2], a3=v[da_*4+3]; \
    _Pragma("unroll") for (int dp_=0; dp_<4; dp_++){ \
        v[da_*4+dp_] = (Mp)[dp_*4+0]*a0 + (Mp)[dp_*4+1]*a1 + (Mp)[dp_*4+2]*a2 + (Mp)[dp_*4+3]*a3; } } }

// ================= fused phase kernel (Pauli rep, fully specialized) =================
// c layout (float index, 20 bits): qubit q at position p(q): q0->0,q5->1,q4->2,q3->3,
//   q2->4,q1->5,q9->6,q8->7,q7->8,q6->9; digit (2-bit Pauli idx: I=0,X=1,Y=2,Z=3)
//   at bits (2p, 2p+1).
// Phase A (ISB=0): tile = bits 0..11 (qubits 0,5,4,3,2,1); block -> bits 12..19.
// Phase B (ISB=1): tile = bits 0..3 + 12..19 (qubits 0,5,9,8,7,6); block -> bits 4..11.
// MODE 2 (last phase): grid=9 LUT blocks, trace = direct entry reads, no store.
template<int LAYER, int ISB, int DOINIT, int MODE>
__global__ void __launch_bounds__(256)
fused6(float* __restrict__ rho, const float* __restrict__ wts, float* __restrict__ cvec)
{
    __shared__ __align__(16) float tile[4096];
    __shared__ float sm[31*16];
    int tid = threadIdx.x;
    unsigned blk = blockIdx.x;
    if (MODE == 2){
        const unsigned LUT[9] = {0,1,3,4,12,16,48,64,192};
        blk = LUT[blockIdx.x];
    }

    prep_sm(sm, wts, tid);      // wave 0 only; waves 1-3 fall through to loads

    unsigned bo = blk << (ISB ? 4 : 12);
    if (DOINIT){
        // c_s = 1 for s in {I,Z}^10 (digit bits equal), else 0
#pragma unroll
        for (int r=0; r<16; r++){
            unsigned u = tid + 256u*r;
            unsigned g = u | bo;
            unsigned e = g & 0x55555u, o = (g>>1) & 0x55555u;
            tile[swz(u)] = (e==o) ? 1.f : 0.f;
        }
    } else {
#pragma unroll
        for (int r=0; r<4; r++){
            unsigned u = 4u*(tid + 256u*r);
            unsigned g = ISB ? ((u & 15u) | ((u>>4)<<12) | bo) : (u | bo);
            *reinterpret_cast<float4*>(&tile[swz(u)]) = *reinterpret_cast<const float4*>(rho + g);
        }
    }
    __syncthreads();

    // op tables (tile bit positions of control/target digit pairs) — compile-time
    constexpr int A_PA[5] = {0,10,8,6,4}, A_PB[5] = {10,8,6,4,2};
    constexpr int B_PA[5] = {2,10,8,6,4}, B_PB[5] = {10,8,6,4,0};

#pragma unroll
    for (int i=0; i<5; i++){
        const int pa = ISB ? B_PA[i] : A_PA[i];
        const int pb = ISB ? B_PB[i] : A_PB[i];
        const int mA = (!ISB && i==0) ? LAYER*160 : -1;               // rot(l,0) on control
        const int mB = !ISB ? (LAYER*10 + i + 1)*16
                            : ((i < 4) ? (LAYER*10 + 6 + i)*16 : -1); // rot(l,6..9)
        const int lo = pa < pb ? pa : pb, hi = pa < pb ? pb : pa;
        unsigned g8 = (unsigned)tid;
        unsigned xx = ((g8 >> lo) << (lo+2)) | (g8 & ((1u<<lo)-1u));
        xx = ((xx >> hi) << (hi+2)) | (xx & ((1u<<hi)-1u));
        unsigned adr[16];
        float v[16];
#pragma unroll
        for (int d=0; d<16; d++){
            unsigned t = xx | ((unsigned)(d>>2) << pa) | ((unsigned)(d&3) << pb);
            adr[d] = swz(t);
            v[d] = tile[adr[d]];
        }
        if (mA >= 0){ const float* M = sm + mA; ALONG_A(M); }
        if (mB >= 0){ const float* M = sm + mB; ALONG_B(M); }
        { // CNOT Pauli-basis signed permutation (v[4*pc+pt], I=0,X=1,Y=2,Z=3):
          // (X,I)<->(X,X) (Y,I)<->(Y,X) (I,Y)<->(Z,Y) (I,Z)<->(Z,Z)
          // (X,Y)<->(Y,Z) (X,Z)<->-(Y,Y); fixed: (I,I),(I,X),(Z,I),(Z,X)
            float t0;
            t0=v[4];  v[4]=v[5];   v[5]=t0;
            t0=v[8];  v[8]=v[9];   v[9]=t0;
            t0=v[2];  v[2]=v[14];  v[14]=t0;
            t0=v[3];  v[3]=v[15];  v[15]=t0;
            t0=v[6];  v[6]=v[11];  v[11]=t0;
            t0=v[7];  v[7]=-v[10]; v[10]=-t0;
        }
        { const float* M = sm + 480; ALONG_B(M); ALONG_A(M); }   // N2 target, N2 control
#pragma unroll
        for (int d=0; d<16; d++) tile[adr[d]] = v[d];
        __syncthreads();
    }

    if (MODE != 2){
#pragma unroll
        for (int r=0; r<4; r++){
            unsigned u = 4u*(tid + 256u*r);
            unsigned g = ISB ? ((u & 15u) | ((u>>4)<<12) | bo) : (u | bo);
            *reinterpret_cast<float4*>(rho + g) = *reinterpret_cast<const float4*>(&tile[swz(u)]);
        }
        return;
    }

    // ---- MODE 2: trace = direct coefficient reads; c is dead, no store ----
    // exps(X_q) = c[digit q = X, rest I]; exps(Z_q) = c[digit q = Z, rest I].
    // Tile slot i -> qubit {0,5,9,8,7,6}; block digit j -> qubit {4,3,2,1}.
    if (blk == 0){
        if (tid < 12){
            const int TQ[6] = {0,5,9,8,7,6};
            int i = tid >> 1, isZ = tid & 1;
            unsigned u = (isZ ? 3u : 1u) << (2*i);
            cvec[2*TQ[i] + isZ] = tile[swz(u)];
        }
    } else if (tid == 0){
        const int BQ[4] = {4,3,2,1};
#pragma unroll
        for (int j=0; j<4; j++){
            if (blk == (1u<<(2*j))) cvec[2*BQ[j]]   = tile[0];
            if (blk == (3u<<(2*j))) cvec[2*BQ[j]+1] = tile[0];
        }
    }
}

// ================= head: logits + sigmoid =================
__global__ void __launch_bounds__(256)
logits_kernel(const float* __restrict__ x, const float* __restrict__ bvec,
              const float* __restrict__ cvec, const float* __restrict__ w,
              float* __restrict__ out)
{
    __shared__ float xs[1024];
    __shared__ float cX[10], cZ[10];
    __shared__ float red[4];
    int b = blockIdx.x, tid = threadIdx.x;
    if (tid < 10){
        cX[tid] = w[2*tid] * cvec[2*tid];
        cZ[tid] = 0.96f * w[2*tid+1] * cvec[2*tid+1];   // readout bitflip folded: Z *= 1-2*0.02
    }
    {
        float4 xv = reinterpret_cast<const float4*>(x + (size_t)b*1024)[tid];
        float4 bv = reinterpret_cast<const float4*>(bvec)[tid];
        xs[tid*4+0] = xv.x + bv.x;
        xs[tid*4+1] = xv.y + bv.y;
        xs[tid*4+2] = xv.z + bv.z;
        xs[tid*4+3] = xv.w + bv.w;
    }
    __syncthreads();
    float acc = 0.f;
#pragma unroll
    for (int r=0; r<4; r++){
        int m = tid + r*256;
        float xm = xs[m];
        float sd = 0.f;
#pragma unroll
        for (int qq=0; qq<10; qq++){
            float cz = cZ[qq];
            sd += (m & (1<<(9-qq))) ? -cz : cz;
            acc += cX[qq] * xm * xs[m ^ (1<<(9-qq))];
        }
        acc += sd * xm * xm;
    }
    for (int o=32; o>0; o>>=1) acc += __shfl_down(acc, o);
    if ((tid & 63) == 0) red[tid>>6] = acc;
    __syncthreads();
    if (tid == 0){
        float l = red[0]+red[1]+red[2]+red[3];
        out[b] = 1.f / (1.f + expf(-l));
    }
}

// ================= launch =================
extern "C" void kernel_launch(void* const* d_in, const int* in_sizes, int n_in,
                              void* d_out, int out_size, void* d_ws, size_t ws_size,
                              hipStream_t stream) {
    const float* x    = (const float*)d_in[0];   // [2048,1024]
    const float* bvec = (const float*)d_in[1];   // [1024]
    const float* w    = (const float*)d_in[2];   // [20]
    const float* cw   = (const float*)d_in[3];   // [3,10,3]
    float* out = (float*)d_out;

    char* ws = (char*)d_ws;
    float* rho  = (float*)ws;                                    // 2^20 floats = 4 MB
    float* cvec = (float*)(ws + (size_t)(1u<<20)*sizeof(float));
    (void)ws_size; (void)in_sizes; (void)n_in; (void)out_size;

    fused6<0,0,1,0><<<256, 256, 0, stream>>>(rho, cw, cvec);
    fused6<0,1,0,0><<<256, 256, 0, stream>>>(rho, cw, cvec);
    fused6<1,0,0,0><<<256, 256, 0, stream>>>(rho, cw, cvec);
    fused6<1,1,0,0><<<256, 256, 0, stream>>>(rho, cw, cvec);
    fused6<2,0,0,0><<<256, 256, 0, stream>>>(rho, cw, cvec);
    fused6<2,1,0,2><<<9,   256, 0, stream>>>(rho, cw, cvec);
    logits_kernel<<<2048, 256, 0, stream>>>(x, bvec, cvec, w, out);
}